// Round 8
// baseline (243.723 us; speedup 1.0000x reference)
//
#include <hip/hip_runtime.h>
#include <math.h>

#define BATCH 32

// ---------------------------------------------------------------- utilities
__device__ __forceinline__ float eluf(float v) { return v > 0.f ? v : expm1f(v); }
__device__ __forceinline__ float softplusf(float x) {
    return fmaxf(x, 0.f) + log1pf(expf(-fabsf(x)));
}
__device__ __forceinline__ float sigmoidf(float x) { return 1.f / (1.f + expf(-x)); }

// ---------------------------------------------------------------- conv 3x3 stride 2 (VALID)
// L1-traffic-first design. Thread = 1 output px x 8 co. Patch taps are CONSECUTIVE
// columns (stride-2 is between outputs, not within the 3x3 patch), so each row is
// one float2 + one dword (6 load instrs/ci instead of 9; kills the kx-redundant
// L1 line touches that had conv2 at ~59 B/cyc/CU ~= the 64 B/cyc L1 ceiling).
// All h-buffers use EVEN row strides (RSIN/RSOUT) so float2 loads are 8B-aligned.
// Stats: deterministic per-block partials [P][64] (no atomics, no shuffle-tail cost).
template <int CIN, int HIN, int WIN, int RSIN, int HOUT, int WOUT, int RSOUT,
          int G, int BLOCK, int NZ>
__global__ __launch_bounds__(BLOCK, 6) void conv_kernel(
    const float* __restrict__ in, const float* __restrict__ w, const float* __restrict__ bias,
    float* __restrict__ out, float* __restrict__ ps, float* __restrict__ pq)
{
    constexpr int NW = BLOCK / 64;
    __shared__ float red_s[NW][G];
    __shared__ float red_q[NW][G];

    const int b   = blockIdx.x;
    const int co0 = blockIdx.y * G;
    const int t   = threadIdx.x;
    const int px  = blockIdx.z * BLOCK + t;
    const bool active = px < HOUT * WOUT;
    const int p = active ? px : 0;
    const int y = p / WOUT, x = p % WOUT;

    const float* ib = in + (size_t)b * CIN * HIN * RSIN + (2 * y) * RSIN + 2 * x;

    float acc[G];
#pragma unroll
    for (int u = 0; u < G; ++u) acc[u] = bias[co0 + u];

#pragma unroll 2
    for (int ci = 0; ci < CIN; ++ci) {
        const float* ip = ib + (size_t)ci * (HIN * RSIN);
        // 6 independent loads, all 8B/4B aligned (even strides)
        float2 a0 = *(const float2*)(ip);
        float2 a1 = *(const float2*)(ip + RSIN);
        float2 a2 = *(const float2*)(ip + 2 * RSIN);
        float  c0 = ip[2];
        float  c1 = ip[RSIN + 2];
        float  c2 = ip[2 * RSIN + 2];
        const float pch[9] = {a0.x, a0.y, c0, a1.x, a1.y, c1, a2.x, a2.y, c2};

        const float* wc = w + ((size_t)co0 * CIN + ci) * 9;   // block-uniform -> s_load
#pragma unroll
        for (int u = 0; u < G; ++u)
#pragma unroll
            for (int j = 0; j < 9; ++j)
                acc[u] = fmaf(pch[j], wc[u * CIN * 9 + j], acc[u]);
    }

    // ---- write raw output (padded row stride) + deterministic per-block partials
    const int lane = t & 63, wv = t >> 6;
#pragma unroll
    for (int u = 0; u < G; ++u) {
        float v = active ? acc[u] : 0.f;
        if (active)
            out[((size_t)(b * 64 + co0 + u) * HOUT + y) * RSOUT + x] = v;
        float s = v, q = v * v;
#pragma unroll
        for (int off = 32; off > 0; off >>= 1) {
            s += __shfl_down(s, off);
            q += __shfl_down(q, off);
        }
        if (lane == 0) { red_s[wv][u] = s; red_q[wv][u] = q; }
    }
    __syncthreads();
    if (t < 2 * G) {
        const int u = t & (G - 1);
        const bool wantq = t >= G;
        float tt = 0.f;
#pragma unroll
        for (int k = 0; k < NW; ++k) tt += wantq ? red_q[k][u] : red_s[k][u];
        const int slot = (b * NZ + blockIdx.z) * 64 + co0 + u;
        (wantq ? pq : ps)[slot] = tt;
    }
}

// ---------------------------------------------------------------- finalize: partials -> stats
// one block per channel; fixed tree order -> deterministic
template <int P>
__global__ __launch_bounds__(128) void finalize_kernel(
    const float* __restrict__ ps, const float* __restrict__ pq, float* __restrict__ stats)
{
    __shared__ float ls[128], lq[128];
    const int c = blockIdx.x, t = threadIdx.x;
    float s = 0.f, q = 0.f;
    for (int pp = t; pp < P; pp += 128) { s += ps[pp * 64 + c]; q += pq[pp * 64 + c]; }
    ls[t] = s; lq[t] = q;
    __syncthreads();
#pragma unroll
    for (int off = 64; off > 0; off >>= 1) {
        if (t < off) { ls[t] += ls[t + off]; lq[t] += lq[t + off]; }
        __syncthreads();
    }
    if (t == 0) { stats[2 * c] = ls[0]; stats[2 * c + 1] = lq[0]; }
}

// ---------------------------------------------------------------- bn + elu (in place, padded layout)
// PLANE_PAD = HOUT*RSOUT (includes pad cols, transformed harmlessly); NREAL = HOUT*WOUT
template <int PLANE_PAD, int NREAL>
__global__ __launch_bounds__(256) void bnelu_kernel(
    float* __restrict__ h, const float* __restrict__ stats,
    const float* __restrict__ g, const float* __restrict__ be)
{
    const float invN = 1.f / (float)(BATCH * NREAL);
    const long long total = (long long)BATCH * 64 * PLANE_PAD;
    for (long long idx = (long long)blockIdx.x * blockDim.x + threadIdx.x; idx < total;
         idx += (long long)gridDim.x * blockDim.x) {
        int c = (int)((idx / PLANE_PAD) & 63);
        float s = stats[2 * c], q = stats[2 * c + 1];
        float m = s * invN;
        float var = fmaf(q, invN, -m * m);
        float a = g[c] * rsqrtf(var + 1e-5f);
        float bb = fmaf(-a, m, be[c]);
        h[idx] = eluf(fmaf(a, h[idx], bb));
    }
}

// ---------------------------------------------------------------- head: bnelu(h4) + 1x1 convs + params
// h4 layout: [b][c][7][8] (row stride 8)
__global__ __launch_bounds__(256) void head_kernel(
    const float* __restrict__ x4, const float* __restrict__ stats4,
    const float* __restrict__ g4, const float* __restrict__ be4,
    const float* __restrict__ wp, const float* __restrict__ bp,
    const float* __restrict__ wz, const float* __restrict__ bz,
    const float* __restrict__ eps_scale, const float* __restrict__ eps_shift,
    float* __restrict__ params)
{
    __shared__ float xs[64 * 49];
    __shared__ float fe[64 * 49];
    __shared__ float zz[11 * 49];
    __shared__ float ha[64], hb[64];
    const int b = blockIdx.x, t = threadIdx.x;

    if (t < 64) {
        constexpr float invN = 1.f / (float)(BATCH * 49);
        float s = stats4[2 * t], q = stats4[2 * t + 1];
        float m = s * invN;
        float var = fmaf(q, invN, -m * m);
        float a = g4[t] * rsqrtf(var + 1e-5f);
        ha[t] = a;
        hb[t] = fmaf(-a, m, be4[t]);
    }
    __syncthreads();

    for (int i = t; i < 64 * 49; i += 256) {
        int c = i / 49, p = i % 49;
        float v = x4[(size_t)b * 64 * 56 + c * 56 + (p / 7) * 8 + (p % 7)];
        xs[i] = eluf(fmaf(ha[c], v, hb[c]));
    }
    __syncthreads();

    for (int i = t; i < 64 * 49; i += 256) {
        int co = i / 49, p = i % 49;
        float a = bp[co];
        for (int ci = 0; ci < 64; ++ci) a = fmaf(xs[ci * 49 + p], wp[co * 64 + ci], a);
        fe[i] = eluf(a);
    }
    __syncthreads();

    for (int i = t; i < 11 * 49; i += 256) {
        int co = i / 49, p = i % 49;
        float a = bz[co];
        for (int ci = 0; ci < 64; ++ci) a = fmaf(fe[ci * 49 + p], wz[co * 64 + ci], a);
        zz[i] = a;
    }
    __syncthreads();

    if (t < 49) {
        const int i = t / 7, j = t % 7;
        float es0 = eps_scale[((size_t)b * 49 + t) * 2 + 0];
        float es1 = eps_scale[((size_t)b * 49 + t) * 2 + 1];
        float eh0 = eps_shift[((size_t)b * 49 + t) * 2 + 0];
        float eh1 = eps_shift[((size_t)b * 49 + t) * 2 + 1];
        float zs0 = zz[3 * 49 + t] + softplusf(zz[5 * 49 + t]) * es0;
        float zs1 = zz[4 * 49 + t] + softplusf(zz[6 * 49 + t]) * es1;
        float zh0 = zz[7 * 49 + t] + softplusf(zz[9 * 49 + t]) * eh0;
        float zh1 = zz[8 * 49 + t] + softplusf(zz[10 * 49 + t]) * eh1;
        float th = sigmoidf(zs0) * 0.25f;
        float tw = sigmoidf(zs1) * 0.25f;
        float tx = ((float)i / 7.0f + sigmoidf(zh0) / 7.0f) * 2.f - 1.f;
        float ty = ((float)j / 7.0f + sigmoidf(zh1) / 7.0f) * 2.f - 1.f;
        float4* pp = (float4*)params;
        pp[b * 49 + t] = make_float4(th, tw, tx, ty);
    }
}

// ---------------------------------------------------------------- bilinear glimpse sampler
__device__ __forceinline__ float tap(const float* __restrict__ im, int yy, int xx) {
    bool ok = (xx >= 0) & (xx < 128) & (yy >= 0) & (yy < 128);
    int yc = min(max(yy, 0), 127);
    int xc = min(max(xx, 0), 127);
    return ok ? im[yc * 128 + xc] : 0.f;
}

__global__ __launch_bounds__(256) void sampler_kernel(
    const float* __restrict__ img, const float* __restrict__ params,
    float* __restrict__ out)
{
    const int bk = blockIdx.x;       // b*49 + k
    const int b  = bk / 49;
    const float4 pr = ((const float4*)params)[bk];
    const float th = pr.x, tw = pr.y, tx = pr.z, ty = pr.w;

    for (int idx = threadIdx.x; idx < 3072; idx += 256) {
        const int c  = idx >> 10;
        const int gy = (idx >> 5) & 31;
        const int gx = idx & 31;
        float xb = (2.f * gx + 1.f) / 32.f - 1.f;
        float yb = (2.f * gy + 1.f) / 32.f - 1.f;
        float ixn = fmaf(tw, xb, ty);
        float iyn = fmaf(th, yb, tx);
        float px = ((ixn + 1.f) * 128.f - 1.f) * 0.5f;
        float py = ((iyn + 1.f) * 128.f - 1.f) * 0.5f;
        float x0f = floorf(px), y0f = floorf(py);
        float wx = px - x0f, wy = py - y0f;
        int x0 = (int)x0f, y0 = (int)y0f;
        const float* im = img + ((size_t)b * 3 + c) * 16384;
        float v00 = tap(im, y0, x0);
        float v01 = tap(im, y0, x0 + 1);
        float v10 = tap(im, y0 + 1, x0);
        float v11 = tap(im, y0 + 1, x0 + 1);
        float r = v00 * (1.f - wy) * (1.f - wx) + v01 * (1.f - wy) * wx +
                  v10 * wy * (1.f - wx)        + v11 * wy * wx;
        out[(size_t)bk * 3072 + idx] = r;
    }
}

// ---------------------------------------------------------------- launch
extern "C" void kernel_launch(void* const* d_in, const int* in_sizes, int n_in,
                              void* d_out, int out_size, void* d_ws, size_t ws_size,
                              hipStream_t stream)
{
    const float* img       = (const float*)d_in[0];
    const float* eps_scale = (const float*)d_in[1];
    const float* eps_shift = (const float*)d_in[2];
    const float* w1 = (const float*)d_in[3],  *b1 = (const float*)d_in[4];
    const float* g1 = (const float*)d_in[5],  *be1 = (const float*)d_in[6];
    const float* w2 = (const float*)d_in[7],  *b2 = (const float*)d_in[8];
    const float* g2 = (const float*)d_in[9],  *be2 = (const float*)d_in[10];
    const float* w3 = (const float*)d_in[11], *b3 = (const float*)d_in[12];
    const float* g3 = (const float*)d_in[13], *be3 = (const float*)d_in[14];
    const float* w4 = (const float*)d_in[15], *b4 = (const float*)d_in[16];
    const float* g4 = (const float*)d_in[17], *be4 = (const float*)d_in[18];
    const float* wp = (const float*)d_in[19], *bp = (const float*)d_in[20];
    const float* wz = (const float*)d_in[21], *bz = (const float*)d_in[22];

    float* ws     = (float*)d_ws;
    float* stats  = ws;                 // 512: 4 layers x 64ch x {sum, sumsq}
    float* params = ws + 512;           // 6272 = 32*49*4
    float* ps     = ws + 6784;          // 32768 partial sums  (max P=512 x 64)
    float* pq     = ws + 39552;         // 32768 partial sumsq
    float* h1     = ws + 72320;                      // [32][64][63][64] = 8,257,536
    float* h2     = h1 + (size_t)32 * 64 * 63 * 64;  // [32][64][31][32] = 2,031,616
    float* h3     = h2 + (size_t)32 * 64 * 31 * 32;  // [32][64][15][16] =   491,520
    float* h4     = h3 + (size_t)32 * 64 * 15 * 16;  // [32][64][7][8]   =   114,688

    float* outp = (float*)d_out;

    // conv1: 3->64, img(128x128, rs128) -> h1(63x63, rs64). grid z=16, P=512
    conv_kernel<3, 128, 128, 128, 63, 63, 64, 8, 256, 16>
        <<<dim3(32, 8, 16), 256, 0, stream>>>(img, w1, b1, h1, ps, pq);
    finalize_kernel<512><<<64, 128, 0, stream>>>(ps, pq, stats + 0);
    bnelu_kernel<63 * 64, 63 * 63><<<2048, 256, 0, stream>>>(h1, stats + 0, g1, be1);

    // conv2: 64->64, h1 -> h2(31x31, rs32). grid z=4, P=128
    conv_kernel<64, 63, 63, 64, 31, 31, 32, 8, 256, 4>
        <<<dim3(32, 8, 4), 256, 0, stream>>>(h1, w2, b2, h2, ps, pq);
    finalize_kernel<128><<<64, 128, 0, stream>>>(ps, pq, stats + 128);
    bnelu_kernel<31 * 32, 31 * 31><<<2048, 256, 0, stream>>>(h2, stats + 128, g2, be2);

    // conv3: 64->64, h2 -> h3(15x15, rs16). grid z=1, P=32
    conv_kernel<64, 31, 31, 32, 15, 15, 16, 8, 256, 1>
        <<<dim3(32, 8, 1), 256, 0, stream>>>(h2, w3, b3, h3, ps, pq);
    finalize_kernel<32><<<64, 128, 0, stream>>>(ps, pq, stats + 256);
    bnelu_kernel<15 * 16, 15 * 15><<<1024, 256, 0, stream>>>(h3, stats + 256, g3, be3);

    // conv4: 64->64, h3 -> h4(7x7, rs8). grid z=1, P=32
    conv_kernel<64, 15, 15, 16, 7, 7, 8, 8, 64, 1>
        <<<dim3(32, 8, 1), 64, 0, stream>>>(h3, w4, b4, h4, ps, pq);
    finalize_kernel<32><<<64, 128, 0, stream>>>(ps, pq, stats + 384);

    // head fuses bn4+elu; h4 stays raw
    head_kernel<<<32, 256, 0, stream>>>(h4, stats + 384, g4, be4, wp, bp, wz, bz,
                                        eps_scale, eps_shift, params);

    sampler_kernel<<<1568, 256, 0, stream>>>(img, params, outp);
}

// Round 9
// 236.684 us; speedup vs baseline: 1.0297x; 1.0297x over previous
//
#include <hip/hip_runtime.h>
#include <math.h>

#define BATCH 32

// ---------------------------------------------------------------- utilities
__device__ __forceinline__ float eluf(float v) { return v > 0.f ? v : expm1f(v); }
__device__ __forceinline__ float softplusf(float x) {
    return fmaxf(x, 0.f) + log1pf(expf(-fabsf(x)));
}
__device__ __forceinline__ float sigmoidf(float x) { return 1.f / (1.f + expf(-x)); }

// ---------------------------------------------------------------- conv 3x3 stride 2 (VALID)
// PURE kernel: loads, FMAs, stores. No LDS / shfl / syncthreads / atomics
// (R8 lesson: the per-block stats epilogue cost ~6x conv1's math).
// Patch rows are consecutive columns -> float2+dword (6 load insts / ci).
// CIN=64 path register-double-buffers ci-pairs: 12 loads in flight while the
// previous pair's 144 FMAs issue (forced by dataflow, not scheduler hints).
// Row strides RSIN/RSOUT are even => float2 aligned. Stats done elsewhere.
template <int CIN, int HIN, int RSIN, int HOUT, int WOUT, int RSOUT, int G, int BLOCK>
__global__ __launch_bounds__(BLOCK, 4) void conv_kernel(
    const float* __restrict__ in, const float* __restrict__ w,
    const float* __restrict__ bias, float* __restrict__ out)
{
    const int b   = blockIdx.x;
    const int co0 = blockIdx.y * G;
    const int t   = threadIdx.x;
    const int px  = blockIdx.z * BLOCK + t;
    const bool active = px < HOUT * WOUT;
    const int p = active ? px : 0;
    const int y = p / WOUT, x = p % WOUT;

    const float* ib = in + (size_t)b * CIN * HIN * RSIN + (2 * y) * RSIN + 2 * x;

    float acc[G];
#pragma unroll
    for (int u = 0; u < G; ++u) acc[u] = bias[co0 + u];

#define LOADPAIR(dst, ci)                                                   \
    {                                                                       \
        _Pragma("unroll")                                                   \
        for (int h_ = 0; h_ < 2; ++h_) {                                    \
            const float* ip = ib + (size_t)((ci) + h_) * (HIN * RSIN);      \
            float2 a0 = *(const float2*)(ip);                               \
            float2 a1 = *(const float2*)(ip + RSIN);                        \
            float2 a2 = *(const float2*)(ip + 2 * RSIN);                    \
            float  c0 = ip[2];                                              \
            float  c1 = ip[RSIN + 2];                                       \
            float  c2 = ip[2 * RSIN + 2];                                   \
            dst[h_ * 9 + 0] = a0.x; dst[h_ * 9 + 1] = a0.y; dst[h_ * 9 + 2] = c0; \
            dst[h_ * 9 + 3] = a1.x; dst[h_ * 9 + 4] = a1.y; dst[h_ * 9 + 5] = c1; \
            dst[h_ * 9 + 6] = a2.x; dst[h_ * 9 + 7] = a2.y; dst[h_ * 9 + 8] = c2; \
        }                                                                   \
    }

#define FMAPAIR(src, ci)                                                    \
    {                                                                       \
        const float* wc = w + (size_t)co0 * CIN * 9 + (ci) * 9;             \
        _Pragma("unroll")                                                   \
        for (int u = 0; u < G; ++u)                                         \
            _Pragma("unroll")                                               \
            for (int k = 0; k < 18; ++k)                                    \
                acc[u] = fmaf(src[k], wc[(size_t)u * CIN * 9 + k], acc[u]); \
    }

    if constexpr (CIN == 3) {
        float pch[27];
#pragma unroll
        for (int h_ = 0; h_ < 3; ++h_) {
            const float* ip = ib + (size_t)h_ * (HIN * RSIN);
            float2 a0 = *(const float2*)(ip);
            float2 a1 = *(const float2*)(ip + RSIN);
            float2 a2 = *(const float2*)(ip + 2 * RSIN);
            pch[h_ * 9 + 0] = a0.x; pch[h_ * 9 + 1] = a0.y; pch[h_ * 9 + 2] = ip[2];
            pch[h_ * 9 + 3] = a1.x; pch[h_ * 9 + 4] = a1.y; pch[h_ * 9 + 5] = ip[RSIN + 2];
            pch[h_ * 9 + 6] = a2.x; pch[h_ * 9 + 7] = a2.y; pch[h_ * 9 + 8] = ip[2 * RSIN + 2];
        }
#pragma unroll
        for (int u = 0; u < G; ++u)
#pragma unroll
            for (int k = 0; k < 27; ++k)
                acc[u] = fmaf(pch[k], w[(size_t)(co0 + u) * 27 + k], acc[u]);
    } else {
        float pA[18], pB[18];
        LOADPAIR(pA, 0)
#pragma unroll 1
        for (int ci0 = 0; ci0 + 4 < CIN; ci0 += 4) {
            LOADPAIR(pB, ci0 + 2)
            FMAPAIR(pA, ci0)
            LOADPAIR(pA, ci0 + 4)
            FMAPAIR(pB, ci0 + 2)
        }
        LOADPAIR(pB, CIN - 2)
        FMAPAIR(pA, CIN - 4)
        FMAPAIR(pB, CIN - 2)
    }
#undef LOADPAIR
#undef FMAPAIR

    if (active) {
#pragma unroll
        for (int u = 0; u < G; ++u)
            out[((size_t)(b * 64 + co0 + u) * HOUT + y) * RSOUT + x] = acc[u];
    }
}

// ---------------------------------------------------------------- stats: raw h -> per-split partial [8][64][2]
// block (c, split): lane-local float4 accumulation (pad col masked), one
// wave-reduce per block. Deterministic (fixed order, no atomics).
template <int PLANE_PAD, int RSOUT, int BPS>
__global__ __launch_bounds__(256) void stats_kernel(
    const float* __restrict__ h, float* __restrict__ partial)
{
    const int c = blockIdx.x, sp = blockIdx.y, t = threadIdx.x;
    constexpr int N4 = PLANE_PAD / 4;
    constexpr int Q  = RSOUT / 4;         // pow2; float4 i contains the pad col iff i%Q==Q-1
    float s = 0.f, q = 0.f;
    for (int bb = sp * BPS; bb < (sp + 1) * BPS; ++bb) {
        const float4* pp = (const float4*)(h + (size_t)(bb * 64 + c) * PLANE_PAD);
        for (int i = t; i < N4; i += 256) {
            float4 v = pp[i];
            float w_ = ((i & (Q - 1)) == (Q - 1)) ? 0.f : v.w;
            s += v.x + v.y + v.z + w_;
            q += v.x * v.x + v.y * v.y + v.z * v.z + w_ * w_;
        }
    }
    __shared__ float ls[4], lq[4];
    const int lane = t & 63, wv = t >> 6;
#pragma unroll
    for (int off = 32; off > 0; off >>= 1) {
        s += __shfl_down(s, off);
        q += __shfl_down(q, off);
    }
    if (lane == 0) { ls[wv] = s; lq[wv] = q; }
    __syncthreads();
    if (t == 0) {
        s = ls[0] + ls[1] + ls[2] + ls[3];
        q = lq[0] + lq[1] + lq[2] + lq[3];
        partial[(sp * 64 + c) * 2 + 0] = s;
        partial[(sp * 64 + c) * 2 + 1] = q;
    }
}

// ---------------------------------------------------------------- bn + elu (in place, float4, padded layout)
template <int PLANE_PAD, int NREAL>
__global__ __launch_bounds__(256) void bnelu_kernel(
    float* __restrict__ h, const float* __restrict__ partial,
    const float* __restrict__ g, const float* __restrict__ be)
{
    __shared__ float sa[64], sb[64];
    const int t = threadIdx.x;
    if (t < 64) {
        float s = 0.f, q = 0.f;
#pragma unroll
        for (int k = 0; k < 8; ++k) {
            s += partial[(k * 64 + t) * 2 + 0];
            q += partial[(k * 64 + t) * 2 + 1];
        }
        constexpr float invN = 1.f / (float)(BATCH * NREAL);
        float m = s * invN;
        float var = fmaf(q, invN, -m * m);
        float a = g[t] * rsqrtf(var + 1e-5f);
        sa[t] = a;
        sb[t] = fmaf(-a, m, be[t]);
    }
    __syncthreads();

    const long long total4 = (long long)BATCH * 64 * PLANE_PAD / 4;
    float4* h4 = (float4*)h;
    for (long long i4 = (long long)blockIdx.x * 256 + t; i4 < total4;
         i4 += (long long)gridDim.x * 256) {
        int c = (int)((i4 * 4 / PLANE_PAD) & 63);
        float a = sa[c], bb = sb[c];
        float4 v = h4[i4];
        v.x = eluf(fmaf(a, v.x, bb));
        v.y = eluf(fmaf(a, v.y, bb));
        v.z = eluf(fmaf(a, v.z, bb));
        v.w = eluf(fmaf(a, v.w, bb));
        h4[i4] = v;
    }
}

// ---------------------------------------------------------------- head: bn4+elu + 1x1 convs + params
// h4 layout: [b][c][7][8] (row stride 8); partial4 = [8][64][2]
__global__ __launch_bounds__(256) void head_kernel(
    const float* __restrict__ x4, const float* __restrict__ partial4,
    const float* __restrict__ g4, const float* __restrict__ be4,
    const float* __restrict__ wp, const float* __restrict__ bp,
    const float* __restrict__ wz, const float* __restrict__ bz,
    const float* __restrict__ eps_scale, const float* __restrict__ eps_shift,
    float* __restrict__ params)
{
    __shared__ float xs[64 * 49];
    __shared__ float fe[64 * 49];
    __shared__ float zz[11 * 49];
    __shared__ float ha[64], hb[64];
    const int b = blockIdx.x, t = threadIdx.x;

    if (t < 64) {
        float s = 0.f, q = 0.f;
#pragma unroll
        for (int k = 0; k < 8; ++k) {
            s += partial4[(k * 64 + t) * 2 + 0];
            q += partial4[(k * 64 + t) * 2 + 1];
        }
        constexpr float invN = 1.f / (float)(BATCH * 49);
        float m = s * invN;
        float var = fmaf(q, invN, -m * m);
        float a = g4[t] * rsqrtf(var + 1e-5f);
        ha[t] = a;
        hb[t] = fmaf(-a, m, be4[t]);
    }
    __syncthreads();

    for (int i = t; i < 64 * 49; i += 256) {
        int c = i / 49, p = i % 49;
        float v = x4[(size_t)b * 64 * 56 + c * 56 + (p / 7) * 8 + (p % 7)];
        xs[i] = eluf(fmaf(ha[c], v, hb[c]));
    }
    __syncthreads();

    for (int i = t; i < 64 * 49; i += 256) {
        int co = i / 49, p = i % 49;
        float a = bp[co];
        for (int ci = 0; ci < 64; ++ci) a = fmaf(xs[ci * 49 + p], wp[co * 64 + ci], a);
        fe[i] = eluf(a);
    }
    __syncthreads();

    for (int i = t; i < 11 * 49; i += 256) {
        int co = i / 49, p = i % 49;
        float a = bz[co];
        for (int ci = 0; ci < 64; ++ci) a = fmaf(fe[ci * 49 + p], wz[co * 64 + ci], a);
        zz[i] = a;
    }
    __syncthreads();

    if (t < 49) {
        const int i = t / 7, j = t % 7;
        float es0 = eps_scale[((size_t)b * 49 + t) * 2 + 0];
        float es1 = eps_scale[((size_t)b * 49 + t) * 2 + 1];
        float eh0 = eps_shift[((size_t)b * 49 + t) * 2 + 0];
        float eh1 = eps_shift[((size_t)b * 49 + t) * 2 + 1];
        float zs0 = zz[3 * 49 + t] + softplusf(zz[5 * 49 + t]) * es0;
        float zs1 = zz[4 * 49 + t] + softplusf(zz[6 * 49 + t]) * es1;
        float zh0 = zz[7 * 49 + t] + softplusf(zz[9 * 49 + t]) * eh0;
        float zh1 = zz[8 * 49 + t] + softplusf(zz[10 * 49 + t]) * eh1;
        float th = sigmoidf(zs0) * 0.25f;
        float tw = sigmoidf(zs1) * 0.25f;
        float tx = ((float)i / 7.0f + sigmoidf(zh0) / 7.0f) * 2.f - 1.f;
        float ty = ((float)j / 7.0f + sigmoidf(zh1) / 7.0f) * 2.f - 1.f;
        float4* pp = (float4*)params;
        pp[b * 49 + t] = make_float4(th, tw, tx, ty);
    }
}

// ---------------------------------------------------------------- bilinear glimpse sampler
__device__ __forceinline__ float tap(const float* __restrict__ im, int yy, int xx) {
    bool ok = (xx >= 0) & (xx < 128) & (yy >= 0) & (yy < 128);
    int yc = min(max(yy, 0), 127);
    int xc = min(max(xx, 0), 127);
    return ok ? im[yc * 128 + xc] : 0.f;
}

__global__ __launch_bounds__(256) void sampler_kernel(
    const float* __restrict__ img, const float* __restrict__ params,
    float* __restrict__ out)
{
    const int bk = blockIdx.x;       // b*49 + k
    const int b  = bk / 49;
    const float4 pr = ((const float4*)params)[bk];
    const float th = pr.x, tw = pr.y, tx = pr.z, ty = pr.w;

    for (int idx = threadIdx.x; idx < 3072; idx += 256) {
        const int c  = idx >> 10;
        const int gy = (idx >> 5) & 31;
        const int gx = idx & 31;
        float xb = (2.f * gx + 1.f) / 32.f - 1.f;
        float yb = (2.f * gy + 1.f) / 32.f - 1.f;
        float ixn = fmaf(tw, xb, ty);
        float iyn = fmaf(th, yb, tx);
        float px = ((ixn + 1.f) * 128.f - 1.f) * 0.5f;
        float py = ((iyn + 1.f) * 128.f - 1.f) * 0.5f;
        float x0f = floorf(px), y0f = floorf(py);
        float wx = px - x0f, wy = py - y0f;
        int x0 = (int)x0f, y0 = (int)y0f;
        const float* im = img + ((size_t)b * 3 + c) * 16384;
        float v00 = tap(im, y0, x0);
        float v01 = tap(im, y0, x0 + 1);
        float v10 = tap(im, y0 + 1, x0);
        float v11 = tap(im, y0 + 1, x0 + 1);
        float r = v00 * (1.f - wy) * (1.f - wx) + v01 * (1.f - wy) * wx +
                  v10 * wy * (1.f - wx)        + v11 * wy * wx;
        out[(size_t)bk * 3072 + idx] = r;
    }
}

// ---------------------------------------------------------------- launch
extern "C" void kernel_launch(void* const* d_in, const int* in_sizes, int n_in,
                              void* d_out, int out_size, void* d_ws, size_t ws_size,
                              hipStream_t stream)
{
    const float* img       = (const float*)d_in[0];
    const float* eps_scale = (const float*)d_in[1];
    const float* eps_shift = (const float*)d_in[2];
    const float* w1 = (const float*)d_in[3],  *b1 = (const float*)d_in[4];
    const float* g1 = (const float*)d_in[5],  *be1 = (const float*)d_in[6];
    const float* w2 = (const float*)d_in[7],  *b2 = (const float*)d_in[8];
    const float* g2 = (const float*)d_in[9],  *be2 = (const float*)d_in[10];
    const float* w3 = (const float*)d_in[11], *b3 = (const float*)d_in[12];
    const float* g3 = (const float*)d_in[13], *be3 = (const float*)d_in[14];
    const float* w4 = (const float*)d_in[15], *b4 = (const float*)d_in[16];
    const float* g4 = (const float*)d_in[17], *be4 = (const float*)d_in[18];
    const float* wp = (const float*)d_in[19], *bp = (const float*)d_in[20];
    const float* wz = (const float*)d_in[21], *bz = (const float*)d_in[22];

    float* ws     = (float*)d_ws;
    float* params = ws;                  // 6272 = 32*49*4
    float* part1  = ws + 8192;           // 4 x [8][64][2] = 1024 floats each
    float* part2  = ws + 9216;
    float* part3  = ws + 10240;
    float* part4  = ws + 11264;
    float* h1     = ws + 16384;                      // [32][64][63][64] = 8,257,536
    float* h2     = h1 + (size_t)32 * 64 * 63 * 64;  // [32][64][31][32] = 2,031,616
    float* h3     = h2 + (size_t)32 * 64 * 31 * 32;  // [32][64][15][16] =   491,520
    float* h4     = h3 + (size_t)32 * 64 * 15 * 16;  // [32][64][7][8]   =   114,688

    float* outp = (float*)d_out;

    // conv1: 3->64, img(128, rs128) -> h1(63x63, rs64). G=16
    conv_kernel<3, 128, 128, 63, 63, 64, 16, 256>
        <<<dim3(32, 4, 16), 256, 0, stream>>>(img, w1, b1, h1);
    stats_kernel<63 * 64, 64, 4><<<dim3(64, 8), 256, 0, stream>>>(h1, part1);
    bnelu_kernel<63 * 64, 63 * 63><<<2048, 256, 0, stream>>>(h1, part1, g1, be1);

    // conv2: 64->64, h1 -> h2(31x31, rs32). G=8
    conv_kernel<64, 63, 64, 31, 31, 32, 8, 256>
        <<<dim3(32, 8, 4), 256, 0, stream>>>(h1, w2, b2, h2);
    stats_kernel<31 * 32, 32, 4><<<dim3(64, 8), 256, 0, stream>>>(h2, part2);
    bnelu_kernel<31 * 32, 31 * 31><<<1984, 256, 0, stream>>>(h2, part2, g2, be2);

    // conv3: 64->64, h2 -> h3(15x15, rs16). G=8
    conv_kernel<64, 31, 32, 15, 15, 16, 8, 256>
        <<<dim3(32, 8, 1), 256, 0, stream>>>(h2, w3, b3, h3);
    stats_kernel<15 * 16, 16, 4><<<dim3(64, 8), 256, 0, stream>>>(h3, part3);
    bnelu_kernel<15 * 16, 15 * 15><<<480, 256, 0, stream>>>(h3, part3, g3, be3);

    // conv4: 64->64, h3 -> h4(7x7, rs8). G=8
    conv_kernel<64, 15, 16, 7, 7, 8, 8, 64>
        <<<dim3(32, 8, 1), 64, 0, stream>>>(h3, w4, b4, h4);
    stats_kernel<7 * 8, 8, 4><<<dim3(64, 8), 256, 0, stream>>>(h4, part4);

    // head fuses bn4+elu (sums part4 itself); h4 stays raw
    head_kernel<<<32, 256, 0, stream>>>(h4, part4, g4, be4, wp, bp, wz, bz,
                                        eps_scale, eps_shift, params);

    sampler_kernel<<<1568, 256, 0, stream>>>(img, params, outp);
}